// Round 12
// baseline (617.236 us; speedup 1.0000x reference)
//
#include <hip/hip_runtime.h>

#define D 128
#define BN_EPS 1e-5f
#define ELLW 64             // max degree slots (Poisson(12.8): P(deg>64) ~ 1e-24)

typedef __bf16 bf16_t;
typedef __bf16 bf16x8 __attribute__((ext_vector_type(8)));
typedef __bf16 bf16x4 __attribute__((ext_vector_type(4)));
typedef __bf16 bf16x2 __attribute__((ext_vector_type(2)));
typedef float floatx4 __attribute__((ext_vector_type(4)));

// ===========================================================================
// prep: zero deg[N] + stats[768] + cnts[3], x fp32 -> hb bf16, swizzle
// weights to MFMA B-frag order. Grid covers n4 = N*D/4.
// ===========================================================================
__global__ void prep(const float* __restrict__ x, bf16_t* __restrict__ hb,
                     const float* __restrict__ W1, const float* __restrict__ W2,
                     bf16_t* __restrict__ Wsw, int* __restrict__ deg,
                     float* __restrict__ stats, int* __restrict__ cnts,
                     int N, int n4) {
  int i = blockIdx.x * blockDim.x + threadIdx.x;
  if (i < n4) {
    float4 v = ((const float4*)x)[i];
    bf16x4 p;
    p[0] = (bf16_t)v.x; p[1] = (bf16_t)v.y; p[2] = (bf16_t)v.z; p[3] = (bf16_t)v.w;
    *(bf16x4*)(hb + (size_t)4 * i) = p;
  }
  if (i < N) deg[i] = 0;
  if (i < 768) stats[i] = 0.f;
  if (i < 3) cnts[i] = 0;
  if (i < 6 * 16384) {
    // B-frag order: lane = quad*16 + (n&15) holds B[k=kc*32+quad*8+j][n]
    int mat = i >> 14;
    int kn = i & 16383;
    int k = kn >> 7;
    int n = kn & 127;
    const float* Wm = (mat < 3) ? (W1 + (size_t)mat * 16384)
                                : (W2 + (size_t)(mat - 3) * 16384);
    float v = Wm[kn];
    int f = ((n >> 4) << 2) | (k >> 5);
    int ln = (((k >> 3) & 3) << 4) | (n & 15);
    int j = k & 7;
    Wsw[(size_t)mat * 16384 + ((f << 6) + ln) * 8 + j] = (bf16_t)v;
  }
}

// ===========================================================================
// ell_fill: one-shot ELL build — atomic slot bump + native 4B scatter.
// ===========================================================================
__global__ void ell_fill(const int* __restrict__ src, const int* __restrict__ dst,
                         int* __restrict__ deg, int* __restrict__ ell, int E) {
  int e = blockIdx.x * blockDim.x + threadIdx.x;
  if (e < E) {
    int d = dst[e];
    int slot = atomicAdd(&deg[d], 1);
    if (slot < ELLW) ell[(size_t)d * ELLW + slot] = src[e];
  }
}

// ===========================================================================
// aggregate: z[v] = h[v] + sum_{u in N(v)} h[u] — one wave per node
// (12500 blocks; oversubscription is mandatory for this gather: R5/R8).
// ===========================================================================
__global__ __launch_bounds__(256) void aggregate(
    const bf16_t* __restrict__ h, bf16_t* __restrict__ z,
    const int* __restrict__ ell, const int* __restrict__ deg, int Nn) {
  int node = blockIdx.x * 4 + (threadIdx.x >> 6);
  if (node >= Nn) return;
  int lane = threadIdx.x & 63;
  int off = lane << 1;
  int dg = deg[node]; if (dg > ELLW) dg = ELLW;
  const int* nb = ell + (size_t)node * ELLW;

  bf16x2 sv = *(const bf16x2*)(h + (size_t)node * D + off);
  float a0x = (float)sv[0], a0y = (float)sv[1];
  float a1x = 0.f, a1y = 0.f, a2x = 0.f, a2y = 0.f, a3x = 0.f, a3y = 0.f;
  int e = 0;
  for (; e + 4 <= dg; e += 4) {
    int4 i4 = *(const int4*)(nb + e);
    bf16x2 v0 = *(const bf16x2*)(h + (size_t)i4.x * D + off);
    bf16x2 v1 = *(const bf16x2*)(h + (size_t)i4.y * D + off);
    bf16x2 v2 = *(const bf16x2*)(h + (size_t)i4.z * D + off);
    bf16x2 v3 = *(const bf16x2*)(h + (size_t)i4.w * D + off);
    a0x += (float)v0[0]; a0y += (float)v0[1];
    a1x += (float)v1[0]; a1y += (float)v1[1];
    a2x += (float)v2[0]; a2y += (float)v2[1];
    a3x += (float)v3[0]; a3y += (float)v3[1];
  }
  for (; e < dg; ++e) {
    bf16x2 v = *(const bf16x2*)(h + (size_t)nb[e] * D + off);
    a0x += (float)v[0]; a0y += (float)v[1];
  }
  a0x += a1x + a2x + a3x;
  a0y += a1y + a2y + a3y;
  bf16x2 o;
  o[0] = (bf16_t)a0x; o[1] = (bf16_t)a0y;
  *(bf16x2*)(z + (size_t)node * D + off) = o;
}

// ===========================================================================
// fused_mlp: GEMM1 (acc in regs) + BN stats -> device spin barrier ->
// BN coeffs -> BN+ReLU from LDS tile -> GEMM2 -> store.
// One 64-row strip-group per block; 782 blocks all co-resident
// (4 waves, 19.4 KB LDS, ~90 VGPR -> 8 blocks/CU capacity = 2048 >= 782),
// so the spin barrier cannot deadlock.
// ===========================================================================
__global__ __launch_bounds__(256) void fused_mlp(
    const bf16_t* __restrict__ zb, const bf16_t* __restrict__ Ws1,
    const bf16_t* __restrict__ Ws2, const float* __restrict__ b1l,
    const float* __restrict__ b2l, const float* __restrict__ gl,
    const float* __restrict__ btl, float* __restrict__ st,
    int* __restrict__ ctr, void* __restrict__ outp,
    int nStrips, int N, float invN, int relu_out, int fp32_out, int nBlocks) {
  __shared__ bf16_t T[64][136];     // raw-Y transpose tile (+8 pad)
  __shared__ float sred[256];
  __shared__ float abL[256];

  const int t = threadIdx.x;
  const int wv = t >> 6;
  const int lane = t & 63;
  const int l15 = lane & 15;
  const int quad = lane >> 4;
  const int strip = blockIdx.x * 4 + wv;
  const bool active = strip < nStrips;

  sred[t] = 0.f;

  // ---- GEMM1: A-frags direct from global (row-major == A-frag order) ----
  bf16x8 a[4];
  const int row = strip * 16 + l15;
  if (active && row < N) {
#pragma unroll
    for (int kc = 0; kc < 4; ++kc)
      a[kc] = *(const bf16x8*)(zb + (size_t)row * D + kc * 32 + quad * 8);
  } else {
#pragma unroll
    for (int kc = 0; kc < 4; ++kc)
#pragma unroll
      for (int j = 0; j < 8; ++j) a[kc][j] = (bf16_t)0.f;
  }

  floatx4 acc[8];
#pragma unroll
  for (int nt = 0; nt < 8; ++nt) {
    float bv = b1l[nt * 16 + l15];
    acc[nt] = (floatx4){bv, bv, bv, bv};
  }
#pragma unroll
  for (int nt = 0; nt < 8; ++nt) {
#pragma unroll
    for (int kc = 0; kc < 4; ++kc) {
      bf16x8 b = *(const bf16x8*)(Ws1 + (size_t)((nt * 4 + kc) * 64 + lane) * 8);
      acc[nt] = __builtin_amdgcn_mfma_f32_16x16x32_bf16(a[kc], b, acc[nt], 0, 0, 0);
    }
  }

  // ---- raw-Y -> LDS transpose (before the barrier wait; wave-private rows)
  const int lr = wv * 16 + quad * 4;
#pragma unroll
  for (int nt = 0; nt < 8; ++nt) {
    int c = nt * 16 + l15;
#pragma unroll
    for (int r = 0; r < 4; ++r) T[lr + r][c] = (bf16_t)acc[nt][r];
  }

  // ---- BN stats: wave shuffle reduce -> LDS -> global atomics ----
  const int rowBase = strip * 16 + quad * 4;
  __syncthreads();            // sred init visible to all waves
#pragma unroll
  for (int nt = 0; nt < 8; ++nt) {
    int c = nt * 16 + l15;
    float s = 0.f, q = 0.f;
    if (active) {
#pragma unroll
      for (int r = 0; r < 4; ++r) {
        if (rowBase + r < N) {
          float v = acc[nt][r];
          s += v; q += v * v;
        }
      }
    }
    s += __shfl_xor(s, 16); s += __shfl_xor(s, 32);
    q += __shfl_xor(q, 16); q += __shfl_xor(q, 32);
    if (quad == 0) {
      atomicAdd(&sred[c], s);
      atomicAdd(&sred[128 + c], q);
    }
  }
  __syncthreads();
  atomicAdd(&st[t], sred[t]);
  __threadfence();
  __syncthreads();            // all 256 global atomics + fences done
  if (t == 0) {
    __hip_atomic_fetch_add(ctr, 1, __ATOMIC_RELEASE, __HIP_MEMORY_SCOPE_AGENT);
    while (__hip_atomic_load(ctr, __ATOMIC_ACQUIRE, __HIP_MEMORY_SCOPE_AGENT)
           < nBlocks) { }
  }
  __syncthreads();            // barrier passed for whole block

  // ---- BN coeffs (atomic loads: XCD-coherence-safe) ----
  if (t < 128) {
    float s = __hip_atomic_load(&st[t], __ATOMIC_RELAXED, __HIP_MEMORY_SCOPE_AGENT);
    float q = __hip_atomic_load(&st[128 + t], __ATOMIC_RELAXED, __HIP_MEMORY_SCOPE_AGENT);
    float mu = s * invN;
    float var = fmaxf(q * invN - mu * mu, 0.f);
    float av = gl[t] * rsqrtf(var + BN_EPS);
    abL[t] = av;
    abL[128 + t] = btl[t] - mu * av;
  }
  __syncthreads();

  // ---- P = relu(a*Y+b) read from T in A-frag layout (BN is per-column) ----
  if (active) {
    bf16x8 a2[4];
#pragma unroll
    for (int kc = 0; kc < 4; ++kc) {
      bf16x8 y = *(const bf16x8*)&T[wv * 16 + l15][kc * 32 + quad * 8];
#pragma unroll
      for (int j = 0; j < 8; ++j) {
        int c = kc * 32 + quad * 8 + j;
        float v = fmaxf(fmaf((float)y[j], abL[c], abL[128 + c]), 0.f);
        a2[kc][j] = (bf16_t)v;
      }
    }

    floatx4 acc2[8];
#pragma unroll
    for (int nt = 0; nt < 8; ++nt) {
      float bv = b2l[nt * 16 + l15];
      acc2[nt] = (floatx4){bv, bv, bv, bv};
    }
#pragma unroll
    for (int nt = 0; nt < 8; ++nt) {
#pragma unroll
      for (int kc = 0; kc < 4; ++kc) {
        bf16x8 b = *(const bf16x8*)(Ws2 + (size_t)((nt * 4 + kc) * 64 + lane) * 8);
        acc2[nt] = __builtin_amdgcn_mfma_f32_16x16x32_bf16(a2[kc], b, acc2[nt], 0, 0, 0);
      }
    }

    if (fp32_out) {
      float* out = (float*)outp;
#pragma unroll
      for (int nt = 0; nt < 8; ++nt) {
        int c = nt * 16 + l15;
#pragma unroll
        for (int r = 0; r < 4; ++r) {
          int rw = rowBase + r;
          if (rw < N) {
            float v = acc2[nt][r];
            if (relu_out) v = fmaxf(v, 0.f);
            out[(size_t)rw * D + c] = v;
          }
        }
      }
    } else {
      bf16_t* out = (bf16_t*)outp;
#pragma unroll
      for (int nt = 0; nt < 8; ++nt) {
        int c = nt * 16 + l15;
#pragma unroll
        for (int r = 0; r < 4; ++r) {
          int rw = rowBase + r;
          if (rw < N) {
            float v = acc2[nt][r];
            if (relu_out) v = fmaxf(v, 0.f);
            out[(size_t)rw * D + c] = (bf16_t)v;
          }
        }
      }
    }
  }
}

// ===========================================================================
extern "C" void kernel_launch(void* const* d_in, const int* in_sizes, int n_in,
                              void* d_out, int out_size, void* d_ws, size_t ws_size,
                              hipStream_t stream) {
  const float* x     = (const float*)d_in[0];
  const float* W1    = (const float*)d_in[1];
  const float* b1    = (const float*)d_in[2];
  const float* gamma = (const float*)d_in[3];
  const float* beta  = (const float*)d_in[4];
  const float* W2    = (const float*)d_in[5];
  const float* b2    = (const float*)d_in[6];
  const int*   ei    = (const int*)d_in[7];

  const int N = in_sizes[0] / D;
  const int E = in_sizes[7] / 2;
  const int* src = ei;
  const int* dst = ei + E;
  float* out = (float*)d_out;

  char* ws = (char*)d_ws;
  size_t bufBytes = (size_t)N * D * sizeof(bf16_t);        // 12.8 MB
  bf16_t* hb   = (bf16_t*)ws;                               // h (bf16)
  bf16_t* zb   = (bf16_t*)(ws + bufBytes);                  // z (bf16)
  int*    ell  = (int*)(ws + 2 * bufBytes);                 // N*64 int = 12.8 MB
  int*    deg  = (int*)((char*)ell + (size_t)N * ELLW * sizeof(int));
  float*  stats = (float*)((char*)deg + (size_t)N * sizeof(int));   // 768 floats
  int*    cnts = (int*)((char*)stats + 768 * sizeof(float));        // 3 ints
  bf16_t* Wsw  = (bf16_t*)((char*)cnts + 16);                       // 6*16384 bf16

  const int n4 = N * D / 4;
  const int prepBlocks = (n4 + 255) / 256;
  const int eb = (E + 255) / 256;
  const int aggBlocks = (N + 3) / 4;
  const int nStrips = (N + 15) / 16;
  const int gemmBlocks = (nStrips + 3) / 4;                 // 782: co-resident
  const float invN = 1.f / (float)N;

  prep<<<prepBlocks, 256, 0, stream>>>(x, hb, W1, W2, Wsw, deg, stats, cnts, N, n4);
  ell_fill<<<eb, 256, 0, stream>>>(src, dst, deg, ell, E);

  for (int i = 0; i < 3; ++i) {
    float* st = stats + (size_t)i * 256;
    aggregate<<<aggBlocks, 256, 0, stream>>>(hb, zb, ell, deg, N);
    void* Ob = (i == 2) ? d_out : (void*)hb;
    fused_mlp<<<gemmBlocks, 256, 0, stream>>>(
        zb, Wsw + (size_t)i * 16384, Wsw + (size_t)(i + 3) * 16384,
        b1 + (size_t)i * D, b2 + (size_t)i * D,
        gamma + (size_t)i * D, beta + (size_t)i * D,
        st, cnts + i, Ob, nStrips, N, invN,
        (i < 2) ? 1 : 0, (i == 2) ? 1 : 0, gemmBlocks);
  }
}